// Round 23
// baseline (389.889 us; speedup 1.0000x reference)
//
#include <hip/hip_runtime.h>

#define T_TOTAL 131072
#define SEGLEN  64
#define WARM    32
#define GSEG    8
#define NBLK    (T_TOTAL / (SEGLEN * GSEG))   // 256
#define SB      8

typedef __attribute__((ext_vector_type(8))) short short8;
typedef __attribute__((ext_vector_type(8))) unsigned short ushort8;
typedef __attribute__((ext_vector_type(4))) unsigned short ushort4v;
typedef __attribute__((ext_vector_type(4))) float f32x4;

__device__ __forceinline__ float sigf(float x) {
  return __builtin_amdgcn_rcpf(1.f + __expf(-x));
}
__device__ __forceinline__ float tanhfast(float x) {
  return 1.f - 2.f * __builtin_amdgcn_rcpf(__expf(2.f * x) + 1.f);
}
__device__ __forceinline__ unsigned short f2bf(float x) {
  unsigned u = __float_as_uint(x);
  return (unsigned short)((u + 0x7FFFu + ((u >> 16) & 1u)) >> 16);
}
__device__ __forceinline__ float bf2f(unsigned short u) {
  return __uint_as_float(((unsigned)u) << 16);
}
__device__ __forceinline__ void load_lds16(const void* g, void* l) {
  __builtin_amdgcn_global_load_lds(
      (const __attribute__((address_space(1))) void*)g,
      (__attribute__((address_space(3))) void*)l, 16, 0, 0);
}

// ---------- pad x [T][8] f32 -> [T][32] bf16; col 8 = 1.0 (bias column)
__global__ __launch_bounds__(256) void pad_x(
    const float* __restrict__ x, unsigned short* __restrict__ xp)
{
  const int t = blockIdx.x * 256 + threadIdx.x;
  const float4 a = reinterpret_cast<const float4*>(x)[t * 2];
  const float4 b = reinterpret_cast<const float4*>(x)[t * 2 + 1];
  ushort8 v;
  v[0] = f2bf(a.x); v[1] = f2bf(a.y); v[2] = f2bf(a.z); v[3] = f2bf(a.w);
  v[4] = f2bf(b.x); v[5] = f2bf(b.y); v[6] = f2bf(b.z); v[7] = f2bf(b.w);
  ushort8 z = {0, 0, 0, 0, 0, 0, 0, 0};
  ushort8 z1 = {0x3F80, 0, 0, 0, 0, 0, 0, 0};
  ushort8* o = reinterpret_cast<ushort8*>(xp) + (size_t)t * 4;
  o[0] = v; o[1] = z1; o[2] = z; o[3] = z;
}

// ---------- projection (layer 1): pre[t][rp] = Wih1'@h0 + bias, bf16.
// Each block covers 2 cb slices (Wl[2] in LDS) -> h0/weight redundancy halves.
template<int KI>
__global__ __launch_bounds__(256) void proj_pre2(
    const unsigned short* __restrict__ in, const float* __restrict__ Wih,
    const float* __restrict__ bih, const float* __restrict__ bhh,
    unsigned short* __restrict__ pre)
{
  constexpr int OPR = KI / 8;
  constexpr int NKC = KI / 32;
  constexpr int NISS = (128 * KI / 8) / 256;
  __shared__ __align__(16) unsigned short inr[128 * KI];       // 32 KB
  __shared__ __align__(16) unsigned short Wl[2][128 * KI];     // 64 KB
  __shared__ float badj[2][128];
  const int tid = threadIdx.x;
  const int l = tid & 63, w = tid >> 6;
  const int c = l & 15, q = l >> 4;
  const int tb = blockIdx.x >> 1, cbh = blockIdx.x & 1;
  const size_t t0 = (size_t)tb * 128;

#pragma unroll
  for (int i = 0; i < NISS; ++i) {
    const int slot = i * 256 + tid;
    const int rr = slot / OPR, o = slot % OPR;
    const int so = (o + rr) & (OPR - 1);
    load_lds16(in + (t0 + rr) * KI + so * 8, &inr[0] + (i * 256 + (tid & ~63)) * 8);
  }
  for (int idx = tid; idx < 2 * 128 * KI; idx += 256) {
    const int half = idx / (128 * KI), rem = idx % (128 * KI);
    const int n = rem / KI, k = rem % KI;
    const int rp = (cbh * 2 + half) * 128 + n;
    const int jm = rp >> 2, g = rp & 3;
    const float wv = Wih[(size_t)(g * 128 + jm) * KI + k];
    const int so = ((k >> 3) + n) & (OPR - 1);
    Wl[half][n * KI + so * 8 + (k & 7)] = f2bf(wv);
  }
  if (tid < 256) {
    const int half = tid >> 7, n = tid & 127;
    const int rp = (cbh * 2 + half) * 128 + n;
    const int jm = rp >> 2, g = rp & 3;
    badj[half][n] = bih[g * 128 + jm] + bhh[g * 128 + jm];
  }
  asm volatile("s_waitcnt vmcnt(0)" ::: "memory");
  __syncthreads();

#pragma unroll
  for (int cbi = 0; cbi < 2; ++cbi) {
    short8 bw[8][NKC];
#pragma unroll
    for (int ct = 0; ct < 8; ++ct)
#pragma unroll
      for (int kc = 0; kc < NKC; ++kc) {
        const int o = ((kc * 4 + q) + (ct * 16 + c)) & (OPR - 1);
        bw[ct][kc] = *reinterpret_cast<const short8*>(&Wl[cbi][(ct * 16 + c) * KI + o * 8]);
      }
#pragma unroll
    for (int rt2 = 0; rt2 < 2; ++rt2) {
      const int rt = w * 2 + rt2;
      short8 afr[NKC];
#pragma unroll
      for (int kc = 0; kc < NKC; ++kc) {
        const int o = ((kc * 4 + q) - c) & (OPR - 1);
        afr[kc] = *reinterpret_cast<const short8*>(&inr[(rt * 16 + c) * KI + o * 8]);
      }
#pragma unroll
      for (int ct = 0; ct < 8; ++ct) {
        const float bb = badj[cbi][ct * 16 + c];
        f32x4 acc = {bb, bb, bb, bb};
#pragma unroll
        for (int kc = 0; kc < NKC; ++kc)
          acc = __builtin_amdgcn_mfma_f32_16x16x32_bf16(afr[kc], bw[ct][kc], acc, 0, 0, 0);
#pragma unroll
        for (int rr = 0; rr < 4; ++rr)
          pre[(t0 + rt * 16 + q * 4 + rr) * 512 + (cbh * 2 + cbi) * 128 + ct * 16 + c] =
              f2bf(acc[rr]);
      }
    }
  }
}

// ---------- layer-0 LSTM: z = Wih0'@xpad[t] + Whh0@h; xpad short8 prefetch.
// bxu bits identical to R22's f32-load+convert path -> numerics unchanged.
__global__ __launch_bounds__(512)
void lstm_l0p(
    const unsigned short* __restrict__ xpad,
    unsigned short* __restrict__ hout,
    const float* __restrict__ Whh, const float* __restrict__ Wih,
    const float* __restrict__ bih, const float* __restrict__ bhh)
{
  __shared__ __align__(16) unsigned short hhist[2][SB][GSEG][144];
  const int tid = threadIdx.x;
  const int l = tid & 63, w = tid >> 6;
  const int c = l & 15, q = l >> 4;
  const int sl = c >> 1, r = c & 1;
  const int s0 = blockIdx.x * GSEG;
  const int sgt0 = (s0 + sl) * SEGLEN - WARM;
  const bool zw = (blockIdx.x == 0) && (sl == 0);

  short8 af[4][4];
#pragma unroll
  for (int ti = 0; ti < 4; ++ti) {
    const int rp = (w * 4 + ti) * 16 + c;
    const int jm = rp >> 2, g = rp & 3;
    const float* wr = Whh + (size_t)(g * 128 + jm) * 128 + q * 8;
#pragma unroll
    for (int kc = 0; kc < 4; ++kc) {
      short8 v;
#pragma unroll
      for (int e = 0; e < 8; ++e) v[e] = (short)f2bf(wr[kc * 32 + e]);
      af[ti][kc] = v;
    }
  }
  short8 afi[4];
#pragma unroll
  for (int ti = 0; ti < 4; ++ti) {
    const int rp = (w * 4 + ti) * 16 + c;
    const int jm = rp >> 2, g = rp & 3;
    short8 v;
#pragma unroll
    for (int e = 0; e < 8; ++e) {
      const int k = q * 8 + e;
      float wv = 0.f;
      if (k < 8) wv = Wih[(size_t)(g * 128 + jm) * 8 + k];
      else if (k == 8) wv = bih[g * 128 + jm] + bhh[g * 128 + jm];
      v[e] = (short)f2bf(wv);
    }
    afi[ti] = v;
  }
  const f32x4 zero4 = {0.f, 0.f, 0.f, 0.f};

  float cs0 = 0.f, cs1 = 0.f;
  for (int i = tid; i < GSEG * 128; i += 512) hhist[1][SB - 1][i >> 7][i & 127] = 0;

  short8 bxe, bxo;
#define LDB(buf, lt_) { \
  int t_ = sgt0 + (lt_); \
  t_ = t_ < 0 ? 0 : (t_ > T_TOTAL - 1 ? T_TOTAL - 1 : t_); \
  buf = *reinterpret_cast<const short8*>(xpad + (size_t)t_ * 32 + q * 8); }

  LDB(bxe, 0)
  __syncthreads();

  const int nb = (SEGLEN + WARM) / SB;   // 12

#define GATE0(j) { \
  const float ig = sigf(zS##j[0]); \
  const float fg = sigf(zS##j[1]); \
  const float gg = tanhfast(zS##j[2]); \
  const float og = sigf(zS##j[3]); \
  cs##j = fmaf(fg, cs##j, ig * gg); \
  float hh = og * tanhfast(cs##j); \
  if (zwarm) { cs##j = 0.f; hh = 0.f; } \
  hhist[pb][s][sl][16 * w + (2 * j + r) * 4 + q] = f2bf(hh); }

#define STEP0(s_, BU, BN) { \
  const int s = (s_); const int lt = bi * SB + s; \
  LDB(BN, lt + 1) \
  const unsigned short* hr = s ? &hhist[pb][s - 1][sl][0] : &hhist[pb ^ 1][SB - 1][sl][0]; \
  short8 bh0 = *reinterpret_cast<const short8*>(hr + q * 8); \
  short8 bh1 = *reinterpret_cast<const short8*>(hr + 32 + q * 8); \
  short8 bh2 = *reinterpret_cast<const short8*>(hr + 64 + q * 8); \
  short8 bh3 = *reinterpret_cast<const short8*>(hr + 96 + q * 8); \
  __builtin_amdgcn_s_setprio(1); \
  f32x4 z0, z1, z2, z3; \
  z0 = __builtin_amdgcn_mfma_f32_16x16x32_bf16(afi[0], BU, zero4, 0, 0, 0); \
  z1 = __builtin_amdgcn_mfma_f32_16x16x32_bf16(afi[1], BU, zero4, 0, 0, 0); \
  z2 = __builtin_amdgcn_mfma_f32_16x16x32_bf16(afi[2], BU, zero4, 0, 0, 0); \
  z3 = __builtin_amdgcn_mfma_f32_16x16x32_bf16(afi[3], BU, zero4, 0, 0, 0); \
  z0 = __builtin_amdgcn_mfma_f32_16x16x32_bf16(af[0][0], bh0, z0, 0, 0, 0); \
  z1 = __builtin_amdgcn_mfma_f32_16x16x32_bf16(af[1][0], bh0, z1, 0, 0, 0); \
  z2 = __builtin_amdgcn_mfma_f32_16x16x32_bf16(af[2][0], bh0, z2, 0, 0, 0); \
  z3 = __builtin_amdgcn_mfma_f32_16x16x32_bf16(af[3][0], bh0, z3, 0, 0, 0); \
  z0 = __builtin_amdgcn_mfma_f32_16x16x32_bf16(af[0][1], bh1, z0, 0, 0, 0); \
  z1 = __builtin_amdgcn_mfma_f32_16x16x32_bf16(af[1][1], bh1, z1, 0, 0, 0); \
  z2 = __builtin_amdgcn_mfma_f32_16x16x32_bf16(af[2][1], bh1, z2, 0, 0, 0); \
  z3 = __builtin_amdgcn_mfma_f32_16x16x32_bf16(af[3][1], bh1, z3, 0, 0, 0); \
  z0 = __builtin_amdgcn_mfma_f32_16x16x32_bf16(af[0][2], bh2, z0, 0, 0, 0); \
  z1 = __builtin_amdgcn_mfma_f32_16x16x32_bf16(af[1][2], bh2, z1, 0, 0, 0); \
  z2 = __builtin_amdgcn_mfma_f32_16x16x32_bf16(af[2][2], bh2, z2, 0, 0, 0); \
  z3 = __builtin_amdgcn_mfma_f32_16x16x32_bf16(af[3][2], bh2, z3, 0, 0, 0); \
  z0 = __builtin_amdgcn_mfma_f32_16x16x32_bf16(af[0][3], bh3, z0, 0, 0, 0); \
  z1 = __builtin_amdgcn_mfma_f32_16x16x32_bf16(af[1][3], bh3, z1, 0, 0, 0); \
  z2 = __builtin_amdgcn_mfma_f32_16x16x32_bf16(af[2][3], bh3, z2, 0, 0, 0); \
  z3 = __builtin_amdgcn_mfma_f32_16x16x32_bf16(af[3][3], bh3, z3, 0, 0, 0); \
  __builtin_amdgcn_s_setprio(0); \
  f32x4 zS0, zS1; \
  _Pragma("unroll") \
  for (int k = 0; k < 4; ++k) { \
    zS0[k] = r ? z1[k] : z0[k]; \
    zS1[k] = r ? z3[k] : z2[k]; \
  } \
  const bool zwarm = zw && (lt < WARM); \
  GATE0(0) GATE0(1) \
  asm volatile("s_waitcnt lgkmcnt(0)" ::: "memory"); \
  __builtin_amdgcn_sched_barrier(0); \
  __builtin_amdgcn_s_barrier(); \
  __builtin_amdgcn_sched_barrier(0); }

  for (int bi = 0; bi < nb; ++bi) {
    const int pb = bi & 1;
    if (bi >= WARM / SB + 1) {
      const int lt0 = (bi - 1) * SB - WARM;
#pragma unroll
      for (int it = 0; it < 2; ++it) {
        const int slot = it * 512 + tid;
        const int frow = slot >> 7, fsl = (slot >> 4) & 7, foc = slot & 15;
        const ushort8 hv = *reinterpret_cast<const ushort8*>(&hhist[pb ^ 1][frow][fsl][foc * 8]);
        *reinterpret_cast<ushort8*>(
            hout + ((size_t)(s0 + fsl) * SEGLEN + lt0 + frow) * 128 + foc * 8) = hv;
      }
    }
#pragma unroll
    for (int s2 = 0; s2 < SB / 2; ++s2) {
      STEP0(2 * s2, bxe, bxo)
      STEP0(2 * s2 + 1, bxo, bxe)
    }
  }
#undef STEP0
#undef GATE0
#undef LDB

  {
    const int pb = (nb - 1) & 1;
    const int lt0 = (nb - 1) * SB - WARM;
#pragma unroll
    for (int it = 0; it < 2; ++it) {
      const int slot = it * 512 + tid;
      const int frow = slot >> 7, fsl = (slot >> 4) & 7, foc = slot & 15;
      const ushort8 hv = *reinterpret_cast<const ushort8*>(&hhist[pb][frow][fsl][foc * 8]);
      *reinterpret_cast<ushort8*>(
          hout + ((size_t)(s0 + fsl) * SEGLEN + lt0 + frow) * 128 + foc * 8) = hv;
    }
  }
}

// ---------- layer-1 LSTM (unchanged): z = Whh@h + pre[t].
__global__ __launch_bounds__(512)
void lstm_seg(
    const unsigned short* __restrict__ pre,
    unsigned short* __restrict__ hout,
    const float* __restrict__ Whh)
{
  __shared__ __align__(16) unsigned short hhist[2][SB][GSEG][144];
  const int tid = threadIdx.x;
  const int l = tid & 63, w = tid >> 6;
  const int c = l & 15, q = l >> 4;
  const int sl = c >> 1, r = c & 1;
  const int s0 = blockIdx.x * GSEG;
  const int sgt0 = (s0 + sl) * SEGLEN - WARM;
  const bool zw = (blockIdx.x == 0) && (sl == 0);

  short8 af[4][4];
#pragma unroll
  for (int ti = 0; ti < 4; ++ti) {
    const int rp = (w * 4 + ti) * 16 + c;
    const int jm = rp >> 2, g = rp & 3;
    const float* wr = Whh + (size_t)(g * 128 + jm) * 128 + q * 8;
#pragma unroll
    for (int kc = 0; kc < 4; ++kc) {
      short8 v;
#pragma unroll
      for (int e = 0; e < 8; ++e) v[e] = (short)f2bf(wr[kc * 32 + e]);
      af[ti][kc] = v;
    }
  }
  const f32x4 zero4 = {0.f, 0.f, 0.f, 0.f};

  float cs0 = 0.f, cs1 = 0.f;
  for (int i = tid; i < GSEG * 128; i += 512) hhist[1][SB - 1][i >> 7][i & 127] = 0;

  ushort4v pve[2], pvo[2];
#define LDP(buf, lt_) { \
  int t_ = sgt0 + (lt_); \
  t_ = t_ < 0 ? 0 : (t_ > T_TOTAL - 1 ? T_TOTAL - 1 : t_); \
  const unsigned short* pp = pre + (size_t)t_ * 512; \
  buf[0] = *reinterpret_cast<const ushort4v*>(pp + (16 * w + r * 4 + q) * 4); \
  buf[1] = *reinterpret_cast<const ushort4v*>(pp + (16 * w + (2 + r) * 4 + q) * 4); }

  LDP(pve, 0)
  __syncthreads();

  const int nb = (SEGLEN + WARM) / SB;   // 12

#define GATE(j, PU) { \
  const float ig = sigf(zS##j[0] + bf2f(PU[j][0])); \
  const float fg = sigf(zS##j[1] + bf2f(PU[j][1])); \
  const float gg = tanhfast(zS##j[2] + bf2f(PU[j][2])); \
  const float og = sigf(zS##j[3] + bf2f(PU[j][3])); \
  cs##j = fmaf(fg, cs##j, ig * gg); \
  float hh = og * tanhfast(cs##j); \
  if (zwarm) { cs##j = 0.f; hh = 0.f; } \
  hhist[pb][s][sl][16 * w + (2 * j + r) * 4 + q] = f2bf(hh); }

#define STEP(s_, PU, PN) { \
  const int s = (s_); const int lt = bi * SB + s; \
  LDP(PN, lt + 1) \
  const unsigned short* hr = s ? &hhist[pb][s - 1][sl][0] : &hhist[pb ^ 1][SB - 1][sl][0]; \
  short8 bh0 = *reinterpret_cast<const short8*>(hr + q * 8); \
  short8 bh1 = *reinterpret_cast<const short8*>(hr + 32 + q * 8); \
  short8 bh2 = *reinterpret_cast<const short8*>(hr + 64 + q * 8); \
  short8 bh3 = *reinterpret_cast<const short8*>(hr + 96 + q * 8); \
  __builtin_amdgcn_s_setprio(1); \
  f32x4 z0, z1, z2, z3; \
  z0 = __builtin_amdgcn_mfma_f32_16x16x32_bf16(af[0][0], bh0, zero4, 0, 0, 0); \
  z1 = __builtin_amdgcn_mfma_f32_16x16x32_bf16(af[1][0], bh0, zero4, 0, 0, 0); \
  z2 = __builtin_amdgcn_mfma_f32_16x16x32_bf16(af[2][0], bh0, zero4, 0, 0, 0); \
  z3 = __builtin_amdgcn_mfma_f32_16x16x32_bf16(af[3][0], bh0, zero4, 0, 0, 0); \
  z0 = __builtin_amdgcn_mfma_f32_16x16x32_bf16(af[0][1], bh1, z0, 0, 0, 0); \
  z1 = __builtin_amdgcn_mfma_f32_16x16x32_bf16(af[1][1], bh1, z1, 0, 0, 0); \
  z2 = __builtin_amdgcn_mfma_f32_16x16x32_bf16(af[2][1], bh1, z2, 0, 0, 0); \
  z3 = __builtin_amdgcn_mfma_f32_16x16x32_bf16(af[3][1], bh1, z3, 0, 0, 0); \
  z0 = __builtin_amdgcn_mfma_f32_16x16x32_bf16(af[0][2], bh2, z0, 0, 0, 0); \
  z1 = __builtin_amdgcn_mfma_f32_16x16x32_bf16(af[1][2], bh2, z1, 0, 0, 0); \
  z2 = __builtin_amdgcn_mfma_f32_16x16x32_bf16(af[2][2], bh2, z2, 0, 0, 0); \
  z3 = __builtin_amdgcn_mfma_f32_16x16x32_bf16(af[3][2], bh2, z3, 0, 0, 0); \
  z0 = __builtin_amdgcn_mfma_f32_16x16x32_bf16(af[0][3], bh3, z0, 0, 0, 0); \
  z1 = __builtin_amdgcn_mfma_f32_16x16x32_bf16(af[1][3], bh3, z1, 0, 0, 0); \
  z2 = __builtin_amdgcn_mfma_f32_16x16x32_bf16(af[2][3], bh3, z2, 0, 0, 0); \
  z3 = __builtin_amdgcn_mfma_f32_16x16x32_bf16(af[3][3], bh3, z3, 0, 0, 0); \
  __builtin_amdgcn_s_setprio(0); \
  f32x4 zS0, zS1; \
  _Pragma("unroll") \
  for (int k = 0; k < 4; ++k) { \
    zS0[k] = r ? z1[k] : z0[k]; \
    zS1[k] = r ? z3[k] : z2[k]; \
  } \
  const bool zwarm = zw && (lt < WARM); \
  GATE(0, PU) GATE(1, PU) \
  asm volatile("s_waitcnt lgkmcnt(0)" ::: "memory"); \
  __builtin_amdgcn_sched_barrier(0); \
  __builtin_amdgcn_s_barrier(); \
  __builtin_amdgcn_sched_barrier(0); }

  for (int bi = 0; bi < nb; ++bi) {
    const int pb = bi & 1;
    if (bi >= WARM / SB + 1) {
      const int lt0 = (bi - 1) * SB - WARM;
#pragma unroll
      for (int it = 0; it < 2; ++it) {
        const int slot = it * 512 + tid;
        const int frow = slot >> 7, fsl = (slot >> 4) & 7, foc = slot & 15;
        const ushort8 hv = *reinterpret_cast<const ushort8*>(&hhist[pb ^ 1][frow][fsl][foc * 8]);
        *reinterpret_cast<ushort8*>(
            hout + ((size_t)(s0 + fsl) * SEGLEN + lt0 + frow) * 128 + foc * 8) = hv;
      }
    }
#pragma unroll
    for (int s2 = 0; s2 < SB / 2; ++s2) {
      STEP(2 * s2, pve, pvo)
      STEP(2 * s2 + 1, pvo, pve)
    }
  }
#undef STEP
#undef GATE
#undef LDP

  {
    const int pb = (nb - 1) & 1;
    const int lt0 = (nb - 1) * SB - WARM;
#pragma unroll
    for (int it = 0; it < 2; ++it) {
      const int slot = it * 512 + tid;
      const int frow = slot >> 7, fsl = (slot >> 4) & 7, foc = slot & 15;
      const ushort8 hv = *reinterpret_cast<const ushort8*>(&hhist[pb][frow][fsl][foc * 8]);
      *reinterpret_cast<ushort8*>(
          hout + ((size_t)(s0 + fsl) * SEGLEN + lt0 + frow) * 128 + foc * 8) = hv;
    }
  }
}

// ---------- MFMA MLP block (unchanged)
template<int KI, int KO, bool AFFINE>
__global__ __launch_bounds__(256, 1) void mlp_mfma(
    const unsigned short* __restrict__ in, const float* __restrict__ Wg,
    const float* __restrict__ bias, const float* __restrict__ ac,
    unsigned short* __restrict__ out, float* __restrict__ part)
{
  constexpr int OPR = KI / 8;
  constexpr int NCT = KO / 16;
  constexpr int NKC = KI / 32;
  constexpr int NISS = KI / 16;
  __shared__ __align__(16) unsigned short inr[128 * KI];
  __shared__ __align__(16) unsigned short Wl[KO * KI];
  __shared__ float badj[KO];
  __shared__ float red[4][2][KO];
  const int tid = threadIdx.x;
  const int l = tid & 63, w = tid >> 6;
  const int c = l & 15, q = l >> 4;
  const size_t t0 = (size_t)blockIdx.x * 128;

#pragma unroll
  for (int i = 0; i < NISS; ++i) {
    const int slot = i * 256 + w * 64 + l;
    const int rr = slot / OPR, o = slot % OPR;
    const int so = (o + rr) & (OPR - 1);
    load_lds16(in + (t0 + rr) * KI + so * 8, &inr[(i * 256 + w * 64) * 8]);
  }
  for (int idx = tid; idx < KO * KI; idx += 256) {
    const int n = idx / KI, k = idx % KI;
    float wv = Wg[idx];
    if constexpr (AFFINE) wv *= ac[k];
    const int so = ((k >> 3) + n) & (OPR - 1);
    Wl[n * KI + so * 8 + (k & 7)] = f2bf(wv);
  }
  if (tid < KO) {
    float s = bias[tid];
    if constexpr (AFFINE) {
      for (int k = 0; k < KI; ++k) s = fmaf(Wg[tid * KI + k], ac[KI + k], s);
    }
    badj[tid] = s;
  }
  asm volatile("s_waitcnt vmcnt(0)" ::: "memory");
  __syncthreads();

  short8 bw[NCT][NKC];
#pragma unroll
  for (int ct = 0; ct < NCT; ++ct)
#pragma unroll
    for (int kc = 0; kc < NKC; ++kc) {
      const int o = ((kc * 4 + q) + (ct * 16 + c)) & (OPR - 1);
      bw[ct][kc] = *reinterpret_cast<const short8*>(&Wl[(ct * 16 + c) * KI + o * 8]);
    }

  float psum[NCT], psq[NCT];
#pragma unroll
  for (int ct = 0; ct < NCT; ++ct) { psum[ct] = 0.f; psq[ct] = 0.f; }

#pragma unroll
  for (int rt2 = 0; rt2 < 2; ++rt2) {
    const int rt = w * 2 + rt2;
    short8 afr[NKC];
#pragma unroll
    for (int kc = 0; kc < NKC; ++kc) {
      const int o = ((kc * 4 + q) - c) & (OPR - 1);
      afr[kc] = *reinterpret_cast<const short8*>(&inr[(rt * 16 + c) * KI + o * 8]);
    }
#pragma unroll
    for (int ct = 0; ct < NCT; ++ct) {
      const float bb = badj[ct * 16 + c];
      f32x4 acc = {bb, bb, bb, bb};
#pragma unroll
      for (int kc = 0; kc < NKC; ++kc)
        acc = __builtin_amdgcn_mfma_f32_16x16x32_bf16(afr[kc], bw[ct][kc], acc, 0, 0, 0);
#pragma unroll
      for (int rr = 0; rr < 4; ++rr) {
        float y = acc[rr];
        y = y >= 0.f ? y : 0.01f * y;
        psum[ct] += y; psq[ct] += y * y;
        out[(t0 + rt * 16 + q * 4 + rr) * KO + ct * 16 + c] = f2bf(y);
      }
    }
  }
#pragma unroll
  for (int ct = 0; ct < NCT; ++ct) {
    float s = psum[ct], qq = psq[ct];
    s += __shfl_xor(s, 16); s += __shfl_xor(s, 32);
    qq += __shfl_xor(qq, 16); qq += __shfl_xor(qq, 32);
    if (l < 16) { red[w][0][ct * 16 + c] = s; red[w][1][ct * 16 + c] = qq; }
  }
  __syncthreads();
  if (tid < KO) {
    float s = 0.f, qq = 0.f;
#pragma unroll
    for (int ww = 0; ww < 4; ++ww) { s += red[ww][0][tid]; qq += red[ww][1][tid]; }
    part[(size_t)blockIdx.x * (2 * KO) + tid] = s;
    part[(size_t)blockIdx.x * (2 * KO) + KO + tid] = qq;
  }
}

__global__ __launch_bounds__(1024) void bn_reduce(
    const float* __restrict__ part, const float* __restrict__ gamma,
    const float* __restrict__ beta, float* __restrict__ ac,
    int nblk, int KO, float invT)
{
  __shared__ float tmp[1024];
  const int tid = threadIdx.x;
  const int twoKO = 2 * KO;
  const int ngrp = 1024 / twoKO;
  const int j = tid % twoKO, grp = tid / twoKO;
  float s = 0.f;
  for (int b = grp; b < nblk; b += ngrp) s += part[(size_t)b * twoKO + j];
  tmp[tid] = s;
  __syncthreads();
  if (tid < twoKO) {
    for (int g = 1; g < ngrp; ++g) s += tmp[g * twoKO + tid];
    tmp[tid] = s;
  }
  __syncthreads();
  if (tid < KO) {
    const float m = tmp[tid] * invT;
    const float v = tmp[KO + tid] * invT - m * m;
    const float inv = 1.f / sqrtf(v + 1e-5f);
    const float a = gamma[tid] * inv;
    ac[tid] = a;
    ac[KO + tid] = beta[tid] - m * a;
  }
}

__global__ __launch_bounds__(256) void final_out(
    const unsigned short* __restrict__ y3, const float* __restrict__ wo,
    const float* __restrict__ bo, const float* __restrict__ ac,
    float* __restrict__ out)
{
  const size_t t = (size_t)blockIdx.x * 256 + threadIdx.x;
  float acc = bo[0];
#pragma unroll
  for (int k = 0; k < 16; ++k) acc = fmaf(wo[k], ac[16 + k], acc);
  const ushort8 v0 = reinterpret_cast<const ushort8*>(y3)[t * 2];
  const ushort8 v1 = reinterpret_cast<const ushort8*>(y3)[t * 2 + 1];
#pragma unroll
  for (int k = 0; k < 8; ++k) acc = fmaf(wo[k] * ac[k], bf2f(v0[k]), acc);
#pragma unroll
  for (int k = 0; k < 8; ++k) acc = fmaf(wo[8 + k] * ac[8 + k], bf2f(v1[k]), acc);
  out[t] = acc;
}

extern "C" void kernel_launch(void* const* d_in, const int* in_sizes, int n_in,
                              void* d_out, int out_size, void* d_ws, size_t ws_size,
                              hipStream_t stream) {
  const float* x    = (const float*)d_in[0];
  const float* Wih0 = (const float*)d_in[1];
  const float* Whh0 = (const float*)d_in[2];
  const float* bih0 = (const float*)d_in[3];
  const float* bhh0 = (const float*)d_in[4];
  const float* Wih1 = (const float*)d_in[5];
  const float* Whh1 = (const float*)d_in[6];
  const float* bih1 = (const float*)d_in[7];
  const float* bhh1 = (const float*)d_in[8];
  const float* w1 = (const float*)d_in[9];  const float* b1 = (const float*)d_in[10];
  const float* g1 = (const float*)d_in[11]; const float* be1 = (const float*)d_in[12];
  const float* w2 = (const float*)d_in[13]; const float* b2 = (const float*)d_in[14];
  const float* g2 = (const float*)d_in[15]; const float* be2 = (const float*)d_in[16];
  const float* w3 = (const float*)d_in[17]; const float* b3 = (const float*)d_in[18];
  const float* g3 = (const float*)d_in[19]; const float* be3 = (const float*)d_in[20];
  const float* wo = (const float*)d_in[21]; const float* bo = (const float*)d_in[22];
  float* out = (float*)d_out;

  const int T = T_TOTAL;
  const size_t MB = 1ull << 20;
  char* w8 = (char*)d_ws;
  unsigned short* h0   = (unsigned short*)(w8);              // [T,128] 32MB
  unsigned short* pre  = (unsigned short*)(w8 + 32 * MB);    // [T,512] 128MB
  unsigned short* h1   = (unsigned short*)(w8 + 160 * MB);   // [T,128] 32MB
  unsigned short* xpad = (unsigned short*)(w8 + 192 * MB);   // [T,32]   8MB
  unsigned short* y1   = (unsigned short*)(w8 + 32 * MB);    // reuse pre region
  unsigned short* y2   = (unsigned short*)(w8 + 48 * MB);
  unsigned short* y3   = (unsigned short*)(w8 + 56 * MB);
  float* part1 = (float*)(w8 + 64 * MB);
  float* part2 = (float*)(w8 + 65 * MB);
  float* part3 = (float*)(w8 + 66 * MB);
  float* ac1   = (float*)(w8 + 67 * MB);
  float* ac2   = (float*)(w8 + 67 * MB + 4096);
  float* ac3   = (float*)(w8 + 67 * MB + 8192);

  pad_x<<<T / 256, 256, 0, stream>>>(x, xpad);
  lstm_l0p<<<NBLK, 512, 0, stream>>>(xpad, h0, Whh0, Wih0, bih0, bhh0);
  proj_pre2<128><<<(T / 128) * 2, 256, 0, stream>>>(h0, Wih1, bih1, bhh1, pre);
  lstm_seg<<<NBLK, 512, 0, stream>>>(pre, h1, Whh1);

  const int NB = T / 128;
  mlp_mfma<128, 64, false><<<NB, 256, 0, stream>>>(h1, w1, b1, nullptr, y1, part1);
  bn_reduce<<<1, 1024, 0, stream>>>(part1, g1, be1, ac1, NB, 64, 1.f / T);
  mlp_mfma<64, 32, true><<<NB, 256, 0, stream>>>(y1, w2, b2, ac1, y2, part2);
  bn_reduce<<<1, 1024, 0, stream>>>(part2, g2, be2, ac2, NB, 32, 1.f / T);
  mlp_mfma<32, 16, true><<<NB, 256, 0, stream>>>(y2, w3, b3, ac2, y3, part3);
  bn_reduce<<<1, 1024, 0, stream>>>(part3, g3, be3, ac3, NB, 16, 1.f / T);
  final_out<<<T / 256, 256, 0, stream>>>(y3, wo, bo, ac3, out);
}

// Round 24
// 327.160 us; speedup vs baseline: 1.1917x; 1.1917x over previous
//
#include <hip/hip_runtime.h>

#define T_TOTAL 131072
#define SEGLEN  64
#define WARM    32
#define GSEG    8
#define NBLK    (T_TOTAL / (SEGLEN * GSEG))   // 256
#define SB      8

typedef __attribute__((ext_vector_type(8))) short short8;
typedef __attribute__((ext_vector_type(8))) unsigned short ushort8;
typedef __attribute__((ext_vector_type(4))) unsigned short ushort4v;
typedef __attribute__((ext_vector_type(4))) float f32x4;

__device__ __forceinline__ float sigf(float x) {
  return __builtin_amdgcn_rcpf(1.f + __expf(-x));
}
__device__ __forceinline__ float tanhfast(float x) {
  return 1.f - 2.f * __builtin_amdgcn_rcpf(__expf(2.f * x) + 1.f);
}
__device__ __forceinline__ unsigned short f2bf(float x) {
  unsigned u = __float_as_uint(x);
  return (unsigned short)((u + 0x7FFFu + ((u >> 16) & 1u)) >> 16);
}
__device__ __forceinline__ float bf2f(unsigned short u) {
  return __uint_as_float(((unsigned)u) << 16);
}
__device__ __forceinline__ void load_lds16(const void* g, void* l) {
  __builtin_amdgcn_global_load_lds(
      (const __attribute__((address_space(1))) void*)g,
      (__attribute__((address_space(3))) void*)l, 16, 0, 0);
}

// ---------- pad x [T][8] f32 -> [T][32] bf16; col 8 = 1.0 (bias column)
__global__ __launch_bounds__(256) void pad_x(
    const float* __restrict__ x, unsigned short* __restrict__ xp)
{
  const int t = blockIdx.x * 256 + threadIdx.x;
  const float4 a = reinterpret_cast<const float4*>(x)[t * 2];
  const float4 b = reinterpret_cast<const float4*>(x)[t * 2 + 1];
  ushort8 v;
  v[0] = f2bf(a.x); v[1] = f2bf(a.y); v[2] = f2bf(a.z); v[3] = f2bf(a.w);
  v[4] = f2bf(b.x); v[5] = f2bf(b.y); v[6] = f2bf(b.z); v[7] = f2bf(b.w);
  ushort8 z = {0, 0, 0, 0, 0, 0, 0, 0};
  ushort8 z1 = {0x3F80, 0, 0, 0, 0, 0, 0, 0};
  ushort8* o = reinterpret_cast<ushort8*>(xp) + (size_t)t * 4;
  o[0] = v; o[1] = z1; o[2] = z; o[3] = z;
}

// ---------- projection (layer 1): pre[t][rp] = Wih1'@h0 + bias, bf16.
// Single cb slice per block (R22-proven: 66 KB LDS, 2 blocks/CU, 93 us).
template<int KI>
__global__ __launch_bounds__(256) void proj_pre(
    const unsigned short* __restrict__ in, const float* __restrict__ Wih,
    const float* __restrict__ bih, const float* __restrict__ bhh,
    unsigned short* __restrict__ pre)
{
  constexpr int OPR = KI / 8;
  constexpr int NKC = KI / 32;
  constexpr int NISS = (128 * KI / 8) / 256;
  __shared__ __align__(16) unsigned short inr[128 * KI];
  __shared__ __align__(16) unsigned short Wl[128 * KI];
  __shared__ float badj[128];
  const int tid = threadIdx.x;
  const int l = tid & 63, w = tid >> 6;
  const int c = l & 15, q = l >> 4;
  const int tb = blockIdx.x >> 2, cb = blockIdx.x & 3;
  const size_t t0 = (size_t)tb * 128;

#pragma unroll
  for (int i = 0; i < NISS; ++i) {
    const int slot = i * 256 + tid;
    const int rr = slot / OPR, o = slot % OPR;
    const int so = (o + rr) & (OPR - 1);
    load_lds16(in + (t0 + rr) * KI + so * 8, &inr[0] + (i * 256 + (tid & ~63)) * 8);
  }
  for (int idx = tid; idx < 128 * KI; idx += 256) {
    const int n = idx / KI, k = idx % KI;
    const int rp = cb * 128 + n;
    const int jm = rp >> 2, g = rp & 3;
    const float wv = Wih[(size_t)(g * 128 + jm) * KI + k];
    const int so = ((k >> 3) + n) & (OPR - 1);
    Wl[n * KI + so * 8 + (k & 7)] = f2bf(wv);
  }
  if (tid < 128) {
    const int rp = cb * 128 + tid;
    const int jm = rp >> 2, g = rp & 3;
    badj[tid] = bih[g * 128 + jm] + bhh[g * 128 + jm];
  }
  asm volatile("s_waitcnt vmcnt(0)" ::: "memory");
  __syncthreads();

  short8 bw[8][NKC];
#pragma unroll
  for (int ct = 0; ct < 8; ++ct)
#pragma unroll
    for (int kc = 0; kc < NKC; ++kc) {
      const int o = ((kc * 4 + q) + (ct * 16 + c)) & (OPR - 1);
      bw[ct][kc] = *reinterpret_cast<const short8*>(&Wl[(ct * 16 + c) * KI + o * 8]);
    }

#pragma unroll
  for (int rt2 = 0; rt2 < 2; ++rt2) {
    const int rt = w * 2 + rt2;
    short8 afr[NKC];
#pragma unroll
    for (int kc = 0; kc < NKC; ++kc) {
      const int o = ((kc * 4 + q) - c) & (OPR - 1);
      afr[kc] = *reinterpret_cast<const short8*>(&inr[(rt * 16 + c) * KI + o * 8]);
    }
#pragma unroll
    for (int ct = 0; ct < 8; ++ct) {
      const float bb = badj[ct * 16 + c];
      f32x4 acc = {bb, bb, bb, bb};
#pragma unroll
      for (int kc = 0; kc < NKC; ++kc)
        acc = __builtin_amdgcn_mfma_f32_16x16x32_bf16(afr[kc], bw[ct][kc], acc, 0, 0, 0);
#pragma unroll
      for (int rr = 0; rr < 4; ++rr)
        pre[(t0 + rt * 16 + q * 4 + rr) * 512 + cb * 128 + ct * 16 + c] = f2bf(acc[rr]);
    }
  }
}

// ---------- layer-0 LSTM: z = Wih0'@xpad[t] + Whh0@h; xpad short8 prefetch.
__global__ __launch_bounds__(512)
void lstm_l0p(
    const unsigned short* __restrict__ xpad,
    unsigned short* __restrict__ hout,
    const float* __restrict__ Whh, const float* __restrict__ Wih,
    const float* __restrict__ bih, const float* __restrict__ bhh)
{
  __shared__ __align__(16) unsigned short hhist[2][SB][GSEG][144];
  const int tid = threadIdx.x;
  const int l = tid & 63, w = tid >> 6;
  const int c = l & 15, q = l >> 4;
  const int sl = c >> 1, r = c & 1;
  const int s0 = blockIdx.x * GSEG;
  const int sgt0 = (s0 + sl) * SEGLEN - WARM;
  const bool zw = (blockIdx.x == 0) && (sl == 0);

  short8 af[4][4];
#pragma unroll
  for (int ti = 0; ti < 4; ++ti) {
    const int rp = (w * 4 + ti) * 16 + c;
    const int jm = rp >> 2, g = rp & 3;
    const float* wr = Whh + (size_t)(g * 128 + jm) * 128 + q * 8;
#pragma unroll
    for (int kc = 0; kc < 4; ++kc) {
      short8 v;
#pragma unroll
      for (int e = 0; e < 8; ++e) v[e] = (short)f2bf(wr[kc * 32 + e]);
      af[ti][kc] = v;
    }
  }
  short8 afi[4];
#pragma unroll
  for (int ti = 0; ti < 4; ++ti) {
    const int rp = (w * 4 + ti) * 16 + c;
    const int jm = rp >> 2, g = rp & 3;
    short8 v;
#pragma unroll
    for (int e = 0; e < 8; ++e) {
      const int k = q * 8 + e;
      float wv = 0.f;
      if (k < 8) wv = Wih[(size_t)(g * 128 + jm) * 8 + k];
      else if (k == 8) wv = bih[g * 128 + jm] + bhh[g * 128 + jm];
      v[e] = (short)f2bf(wv);
    }
    afi[ti] = v;
  }
  const f32x4 zero4 = {0.f, 0.f, 0.f, 0.f};

  float cs0 = 0.f, cs1 = 0.f;
  for (int i = tid; i < GSEG * 128; i += 512) hhist[1][SB - 1][i >> 7][i & 127] = 0;

  short8 bxe, bxo;
#define LDB(buf, lt_) { \
  int t_ = sgt0 + (lt_); \
  t_ = t_ < 0 ? 0 : (t_ > T_TOTAL - 1 ? T_TOTAL - 1 : t_); \
  buf = *reinterpret_cast<const short8*>(xpad + (size_t)t_ * 32 + q * 8); }

  LDB(bxe, 0)
  __syncthreads();

  const int nb = (SEGLEN + WARM) / SB;   // 12

#define GATE0(j) { \
  const float ig = sigf(zS##j[0]); \
  const float fg = sigf(zS##j[1]); \
  const float gg = tanhfast(zS##j[2]); \
  const float og = sigf(zS##j[3]); \
  cs##j = fmaf(fg, cs##j, ig * gg); \
  float hh = og * tanhfast(cs##j); \
  if (zwarm) { cs##j = 0.f; hh = 0.f; } \
  hhist[pb][s][sl][16 * w + (2 * j + r) * 4 + q] = f2bf(hh); }

#define STEP0(s_, BU, BN) { \
  const int s = (s_); const int lt = bi * SB + s; \
  LDB(BN, lt + 1) \
  const unsigned short* hr = s ? &hhist[pb][s - 1][sl][0] : &hhist[pb ^ 1][SB - 1][sl][0]; \
  short8 bh0 = *reinterpret_cast<const short8*>(hr + q * 8); \
  short8 bh1 = *reinterpret_cast<const short8*>(hr + 32 + q * 8); \
  short8 bh2 = *reinterpret_cast<const short8*>(hr + 64 + q * 8); \
  short8 bh3 = *reinterpret_cast<const short8*>(hr + 96 + q * 8); \
  __builtin_amdgcn_s_setprio(1); \
  f32x4 z0, z1, z2, z3; \
  z0 = __builtin_amdgcn_mfma_f32_16x16x32_bf16(afi[0], BU, zero4, 0, 0, 0); \
  z1 = __builtin_amdgcn_mfma_f32_16x16x32_bf16(afi[1], BU, zero4, 0, 0, 0); \
  z2 = __builtin_amdgcn_mfma_f32_16x16x32_bf16(afi[2], BU, zero4, 0, 0, 0); \
  z3 = __builtin_amdgcn_mfma_f32_16x16x32_bf16(afi[3], BU, zero4, 0, 0, 0); \
  z0 = __builtin_amdgcn_mfma_f32_16x16x32_bf16(af[0][0], bh0, z0, 0, 0, 0); \
  z1 = __builtin_amdgcn_mfma_f32_16x16x32_bf16(af[1][0], bh0, z1, 0, 0, 0); \
  z2 = __builtin_amdgcn_mfma_f32_16x16x32_bf16(af[2][0], bh0, z2, 0, 0, 0); \
  z3 = __builtin_amdgcn_mfma_f32_16x16x32_bf16(af[3][0], bh0, z3, 0, 0, 0); \
  z0 = __builtin_amdgcn_mfma_f32_16x16x32_bf16(af[0][1], bh1, z0, 0, 0, 0); \
  z1 = __builtin_amdgcn_mfma_f32_16x16x32_bf16(af[1][1], bh1, z1, 0, 0, 0); \
  z2 = __builtin_amdgcn_mfma_f32_16x16x32_bf16(af[2][1], bh1, z2, 0, 0, 0); \
  z3 = __builtin_amdgcn_mfma_f32_16x16x32_bf16(af[3][1], bh1, z3, 0, 0, 0); \
  z0 = __builtin_amdgcn_mfma_f32_16x16x32_bf16(af[0][2], bh2, z0, 0, 0, 0); \
  z1 = __builtin_amdgcn_mfma_f32_16x16x32_bf16(af[1][2], bh2, z1, 0, 0, 0); \
  z2 = __builtin_amdgcn_mfma_f32_16x16x32_bf16(af[2][2], bh2, z2, 0, 0, 0); \
  z3 = __builtin_amdgcn_mfma_f32_16x16x32_bf16(af[3][2], bh2, z3, 0, 0, 0); \
  z0 = __builtin_amdgcn_mfma_f32_16x16x32_bf16(af[0][3], bh3, z0, 0, 0, 0); \
  z1 = __builtin_amdgcn_mfma_f32_16x16x32_bf16(af[1][3], bh3, z1, 0, 0, 0); \
  z2 = __builtin_amdgcn_mfma_f32_16x16x32_bf16(af[2][3], bh3, z2, 0, 0, 0); \
  z3 = __builtin_amdgcn_mfma_f32_16x16x32_bf16(af[3][3], bh3, z3, 0, 0, 0); \
  __builtin_amdgcn_s_setprio(0); \
  f32x4 zS0, zS1; \
  _Pragma("unroll") \
  for (int k = 0; k < 4; ++k) { \
    zS0[k] = r ? z1[k] : z0[k]; \
    zS1[k] = r ? z3[k] : z2[k]; \
  } \
  const bool zwarm = zw && (lt < WARM); \
  GATE0(0) GATE0(1) \
  asm volatile("s_waitcnt lgkmcnt(0)" ::: "memory"); \
  __builtin_amdgcn_sched_barrier(0); \
  __builtin_amdgcn_s_barrier(); \
  __builtin_amdgcn_sched_barrier(0); }

  for (int bi = 0; bi < nb; ++bi) {
    const int pb = bi & 1;
    if (bi >= WARM / SB + 1) {
      const int lt0 = (bi - 1) * SB - WARM;
#pragma unroll
      for (int it = 0; it < 2; ++it) {
        const int slot = it * 512 + tid;
        const int frow = slot >> 7, fsl = (slot >> 4) & 7, foc = slot & 15;
        const ushort8 hv = *reinterpret_cast<const ushort8*>(&hhist[pb ^ 1][frow][fsl][foc * 8]);
        *reinterpret_cast<ushort8*>(
            hout + ((size_t)(s0 + fsl) * SEGLEN + lt0 + frow) * 128 + foc * 8) = hv;
      }
    }
#pragma unroll
    for (int s2 = 0; s2 < SB / 2; ++s2) {
      STEP0(2 * s2, bxe, bxo)
      STEP0(2 * s2 + 1, bxo, bxe)
    }
  }
#undef STEP0
#undef GATE0
#undef LDB

  {
    const int pb = (nb - 1) & 1;
    const int lt0 = (nb - 1) * SB - WARM;
#pragma unroll
    for (int it = 0; it < 2; ++it) {
      const int slot = it * 512 + tid;
      const int frow = slot >> 7, fsl = (slot >> 4) & 7, foc = slot & 15;
      const ushort8 hv = *reinterpret_cast<const ushort8*>(&hhist[pb][frow][fsl][foc * 8]);
      *reinterpret_cast<ushort8*>(
          hout + ((size_t)(s0 + fsl) * SEGLEN + lt0 + frow) * 128 + foc * 8) = hv;
    }
  }
}

// ---------- layer-1 LSTM (unchanged): z = Whh@h + pre[t].
__global__ __launch_bounds__(512)
void lstm_seg(
    const unsigned short* __restrict__ pre,
    unsigned short* __restrict__ hout,
    const float* __restrict__ Whh)
{
  __shared__ __align__(16) unsigned short hhist[2][SB][GSEG][144];
  const int tid = threadIdx.x;
  const int l = tid & 63, w = tid >> 6;
  const int c = l & 15, q = l >> 4;
  const int sl = c >> 1, r = c & 1;
  const int s0 = blockIdx.x * GSEG;
  const int sgt0 = (s0 + sl) * SEGLEN - WARM;
  const bool zw = (blockIdx.x == 0) && (sl == 0);

  short8 af[4][4];
#pragma unroll
  for (int ti = 0; ti < 4; ++ti) {
    const int rp = (w * 4 + ti) * 16 + c;
    const int jm = rp >> 2, g = rp & 3;
    const float* wr = Whh + (size_t)(g * 128 + jm) * 128 + q * 8;
#pragma unroll
    for (int kc = 0; kc < 4; ++kc) {
      short8 v;
#pragma unroll
      for (int e = 0; e < 8; ++e) v[e] = (short)f2bf(wr[kc * 32 + e]);
      af[ti][kc] = v;
    }
  }
  const f32x4 zero4 = {0.f, 0.f, 0.f, 0.f};

  float cs0 = 0.f, cs1 = 0.f;
  for (int i = tid; i < GSEG * 128; i += 512) hhist[1][SB - 1][i >> 7][i & 127] = 0;

  ushort4v pve[2], pvo[2];
#define LDP(buf, lt_) { \
  int t_ = sgt0 + (lt_); \
  t_ = t_ < 0 ? 0 : (t_ > T_TOTAL - 1 ? T_TOTAL - 1 : t_); \
  const unsigned short* pp = pre + (size_t)t_ * 512; \
  buf[0] = *reinterpret_cast<const ushort4v*>(pp + (16 * w + r * 4 + q) * 4); \
  buf[1] = *reinterpret_cast<const ushort4v*>(pp + (16 * w + (2 + r) * 4 + q) * 4); }

  LDP(pve, 0)
  __syncthreads();

  const int nb = (SEGLEN + WARM) / SB;   // 12

#define GATE(j, PU) { \
  const float ig = sigf(zS##j[0] + bf2f(PU[j][0])); \
  const float fg = sigf(zS##j[1] + bf2f(PU[j][1])); \
  const float gg = tanhfast(zS##j[2] + bf2f(PU[j][2])); \
  const float og = sigf(zS##j[3] + bf2f(PU[j][3])); \
  cs##j = fmaf(fg, cs##j, ig * gg); \
  float hh = og * tanhfast(cs##j); \
  if (zwarm) { cs##j = 0.f; hh = 0.f; } \
  hhist[pb][s][sl][16 * w + (2 * j + r) * 4 + q] = f2bf(hh); }

#define STEP(s_, PU, PN) { \
  const int s = (s_); const int lt = bi * SB + s; \
  LDP(PN, lt + 1) \
  const unsigned short* hr = s ? &hhist[pb][s - 1][sl][0] : &hhist[pb ^ 1][SB - 1][sl][0]; \
  short8 bh0 = *reinterpret_cast<const short8*>(hr + q * 8); \
  short8 bh1 = *reinterpret_cast<const short8*>(hr + 32 + q * 8); \
  short8 bh2 = *reinterpret_cast<const short8*>(hr + 64 + q * 8); \
  short8 bh3 = *reinterpret_cast<const short8*>(hr + 96 + q * 8); \
  __builtin_amdgcn_s_setprio(1); \
  f32x4 z0, z1, z2, z3; \
  z0 = __builtin_amdgcn_mfma_f32_16x16x32_bf16(af[0][0], bh0, zero4, 0, 0, 0); \
  z1 = __builtin_amdgcn_mfma_f32_16x16x32_bf16(af[1][0], bh0, zero4, 0, 0, 0); \
  z2 = __builtin_amdgcn_mfma_f32_16x16x32_bf16(af[2][0], bh0, zero4, 0, 0, 0); \
  z3 = __builtin_amdgcn_mfma_f32_16x16x32_bf16(af[3][0], bh0, zero4, 0, 0, 0); \
  z0 = __builtin_amdgcn_mfma_f32_16x16x32_bf16(af[0][1], bh1, z0, 0, 0, 0); \
  z1 = __builtin_amdgcn_mfma_f32_16x16x32_bf16(af[1][1], bh1, z1, 0, 0, 0); \
  z2 = __builtin_amdgcn_mfma_f32_16x16x32_bf16(af[2][1], bh1, z2, 0, 0, 0); \
  z3 = __builtin_amdgcn_mfma_f32_16x16x32_bf16(af[3][1], bh1, z3, 0, 0, 0); \
  z0 = __builtin_amdgcn_mfma_f32_16x16x32_bf16(af[0][2], bh2, z0, 0, 0, 0); \
  z1 = __builtin_amdgcn_mfma_f32_16x16x32_bf16(af[1][2], bh2, z1, 0, 0, 0); \
  z2 = __builtin_amdgcn_mfma_f32_16x16x32_bf16(af[2][2], bh2, z2, 0, 0, 0); \
  z3 = __builtin_amdgcn_mfma_f32_16x16x32_bf16(af[3][2], bh2, z3, 0, 0, 0); \
  z0 = __builtin_amdgcn_mfma_f32_16x16x32_bf16(af[0][3], bh3, z0, 0, 0, 0); \
  z1 = __builtin_amdgcn_mfma_f32_16x16x32_bf16(af[1][3], bh3, z1, 0, 0, 0); \
  z2 = __builtin_amdgcn_mfma_f32_16x16x32_bf16(af[2][3], bh3, z2, 0, 0, 0); \
  z3 = __builtin_amdgcn_mfma_f32_16x16x32_bf16(af[3][3], bh3, z3, 0, 0, 0); \
  __builtin_amdgcn_s_setprio(0); \
  f32x4 zS0, zS1; \
  _Pragma("unroll") \
  for (int k = 0; k < 4; ++k) { \
    zS0[k] = r ? z1[k] : z0[k]; \
    zS1[k] = r ? z3[k] : z2[k]; \
  } \
  const bool zwarm = zw && (lt < WARM); \
  GATE(0, PU) GATE(1, PU) \
  asm volatile("s_waitcnt lgkmcnt(0)" ::: "memory"); \
  __builtin_amdgcn_sched_barrier(0); \
  __builtin_amdgcn_s_barrier(); \
  __builtin_amdgcn_sched_barrier(0); }

  for (int bi = 0; bi < nb; ++bi) {
    const int pb = bi & 1;
    if (bi >= WARM / SB + 1) {
      const int lt0 = (bi - 1) * SB - WARM;
#pragma unroll
      for (int it = 0; it < 2; ++it) {
        const int slot = it * 512 + tid;
        const int frow = slot >> 7, fsl = (slot >> 4) & 7, foc = slot & 15;
        const ushort8 hv = *reinterpret_cast<const ushort8*>(&hhist[pb ^ 1][frow][fsl][foc * 8]);
        *reinterpret_cast<ushort8*>(
            hout + ((size_t)(s0 + fsl) * SEGLEN + lt0 + frow) * 128 + foc * 8) = hv;
      }
    }
#pragma unroll
    for (int s2 = 0; s2 < SB / 2; ++s2) {
      STEP(2 * s2, pve, pvo)
      STEP(2 * s2 + 1, pvo, pve)
    }
  }
#undef STEP
#undef GATE
#undef LDP

  {
    const int pb = (nb - 1) & 1;
    const int lt0 = (nb - 1) * SB - WARM;
#pragma unroll
    for (int it = 0; it < 2; ++it) {
      const int slot = it * 512 + tid;
      const int frow = slot >> 7, fsl = (slot >> 4) & 7, foc = slot & 15;
      const ushort8 hv = *reinterpret_cast<const ushort8*>(&hhist[pb][frow][fsl][foc * 8]);
      *reinterpret_cast<ushort8*>(
          hout + ((size_t)(s0 + fsl) * SEGLEN + lt0 + frow) * 128 + foc * 8) = hv;
    }
  }
}

// ---------- MFMA MLP block (unchanged)
template<int KI, int KO, bool AFFINE>
__global__ __launch_bounds__(256, 1) void mlp_mfma(
    const unsigned short* __restrict__ in, const float* __restrict__ Wg,
    const float* __restrict__ bias, const float* __restrict__ ac,
    unsigned short* __restrict__ out, float* __restrict__ part)
{
  constexpr int OPR = KI / 8;
  constexpr int NCT = KO / 16;
  constexpr int NKC = KI / 32;
  constexpr int NISS = KI / 16;
  __shared__ __align__(16) unsigned short inr[128 * KI];
  __shared__ __align__(16) unsigned short Wl[KO * KI];
  __shared__ float badj[KO];
  __shared__ float red[4][2][KO];
  const int tid = threadIdx.x;
  const int l = tid & 63, w = tid >> 6;
  const int c = l & 15, q = l >> 4;
  const size_t t0 = (size_t)blockIdx.x * 128;

#pragma unroll
  for (int i = 0; i < NISS; ++i) {
    const int slot = i * 256 + w * 64 + l;
    const int rr = slot / OPR, o = slot % OPR;
    const int so = (o + rr) & (OPR - 1);
    load_lds16(in + (t0 + rr) * KI + so * 8, &inr[(i * 256 + w * 64) * 8]);
  }
  for (int idx = tid; idx < KO * KI; idx += 256) {
    const int n = idx / KI, k = idx % KI;
    float wv = Wg[idx];
    if constexpr (AFFINE) wv *= ac[k];
    const int so = ((k >> 3) + n) & (OPR - 1);
    Wl[n * KI + so * 8 + (k & 7)] = f2bf(wv);
  }
  if (tid < KO) {
    float s = bias[tid];
    if constexpr (AFFINE) {
      for (int k = 0; k < KI; ++k) s = fmaf(Wg[tid * KI + k], ac[KI + k], s);
    }
    badj[tid] = s;
  }
  asm volatile("s_waitcnt vmcnt(0)" ::: "memory");
  __syncthreads();

  short8 bw[NCT][NKC];
#pragma unroll
  for (int ct = 0; ct < NCT; ++ct)
#pragma unroll
    for (int kc = 0; kc < NKC; ++kc) {
      const int o = ((kc * 4 + q) + (ct * 16 + c)) & (OPR - 1);
      bw[ct][kc] = *reinterpret_cast<const short8*>(&Wl[(ct * 16 + c) * KI + o * 8]);
    }

  float psum[NCT], psq[NCT];
#pragma unroll
  for (int ct = 0; ct < NCT; ++ct) { psum[ct] = 0.f; psq[ct] = 0.f; }

#pragma unroll
  for (int rt2 = 0; rt2 < 2; ++rt2) {
    const int rt = w * 2 + rt2;
    short8 afr[NKC];
#pragma unroll
    for (int kc = 0; kc < NKC; ++kc) {
      const int o = ((kc * 4 + q) - c) & (OPR - 1);
      afr[kc] = *reinterpret_cast<const short8*>(&inr[(rt * 16 + c) * KI + o * 8]);
    }
#pragma unroll
    for (int ct = 0; ct < NCT; ++ct) {
      const float bb = badj[ct * 16 + c];
      f32x4 acc = {bb, bb, bb, bb};
#pragma unroll
      for (int kc = 0; kc < NKC; ++kc)
        acc = __builtin_amdgcn_mfma_f32_16x16x32_bf16(afr[kc], bw[ct][kc], acc, 0, 0, 0);
#pragma unroll
      for (int rr = 0; rr < 4; ++rr) {
        float y = acc[rr];
        y = y >= 0.f ? y : 0.01f * y;
        psum[ct] += y; psq[ct] += y * y;
        out[(t0 + rt * 16 + q * 4 + rr) * KO + ct * 16 + c] = f2bf(y);
      }
    }
  }
#pragma unroll
  for (int ct = 0; ct < NCT; ++ct) {
    float s = psum[ct], qq = psq[ct];
    s += __shfl_xor(s, 16); s += __shfl_xor(s, 32);
    qq += __shfl_xor(qq, 16); qq += __shfl_xor(qq, 32);
    if (l < 16) { red[w][0][ct * 16 + c] = s; red[w][1][ct * 16 + c] = qq; }
  }
  __syncthreads();
  if (tid < KO) {
    float s = 0.f, qq = 0.f;
#pragma unroll
    for (int ww = 0; ww < 4; ++ww) { s += red[ww][0][tid]; qq += red[ww][1][tid]; }
    part[(size_t)blockIdx.x * (2 * KO) + tid] = s;
    part[(size_t)blockIdx.x * (2 * KO) + KO + tid] = qq;
  }
}

__global__ __launch_bounds__(1024) void bn_reduce(
    const float* __restrict__ part, const float* __restrict__ gamma,
    const float* __restrict__ beta, float* __restrict__ ac,
    int nblk, int KO, float invT)
{
  __shared__ float tmp[1024];
  const int tid = threadIdx.x;
  const int twoKO = 2 * KO;
  const int ngrp = 1024 / twoKO;
  const int j = tid % twoKO, grp = tid / twoKO;
  float s = 0.f;
  for (int b = grp; b < nblk; b += ngrp) s += part[(size_t)b * twoKO + j];
  tmp[tid] = s;
  __syncthreads();
  if (tid < twoKO) {
    for (int g = 1; g < ngrp; ++g) s += tmp[g * twoKO + tid];
    tmp[tid] = s;
  }
  __syncthreads();
  if (tid < KO) {
    const float m = tmp[tid] * invT;
    const float v = tmp[KO + tid] * invT - m * m;
    const float inv = 1.f / sqrtf(v + 1e-5f);
    const float a = gamma[tid] * inv;
    ac[tid] = a;
    ac[KO + tid] = beta[tid] - m * a;
  }
}

__global__ __launch_bounds__(256) void final_out(
    const unsigned short* __restrict__ y3, const float* __restrict__ wo,
    const float* __restrict__ bo, const float* __restrict__ ac,
    float* __restrict__ out)
{
  const size_t t = (size_t)blockIdx.x * 256 + threadIdx.x;
  float acc = bo[0];
#pragma unroll
  for (int k = 0; k < 16; ++k) acc = fmaf(wo[k], ac[16 + k], acc);
  const ushort8 v0 = reinterpret_cast<const ushort8*>(y3)[t * 2];
  const ushort8 v1 = reinterpret_cast<const ushort8*>(y3)[t * 2 + 1];
#pragma unroll
  for (int k = 0; k < 8; ++k) acc = fmaf(wo[k] * ac[k], bf2f(v0[k]), acc);
#pragma unroll
  for (int k = 0; k < 8; ++k) acc = fmaf(wo[8 + k] * ac[8 + k], bf2f(v1[k]), acc);
  out[t] = acc;
}

extern "C" void kernel_launch(void* const* d_in, const int* in_sizes, int n_in,
                              void* d_out, int out_size, void* d_ws, size_t ws_size,
                              hipStream_t stream) {
  const float* x    = (const float*)d_in[0];
  const float* Wih0 = (const float*)d_in[1];
  const float* Whh0 = (const float*)d_in[2];
  const float* bih0 = (const float*)d_in[3];
  const float* bhh0 = (const float*)d_in[4];
  const float* Wih1 = (const float*)d_in[5];
  const float* Whh1 = (const float*)d_in[6];
  const float* bih1 = (const float*)d_in[7];
  const float* bhh1 = (const float*)d_in[8];
  const float* w1 = (const float*)d_in[9];  const float* b1 = (const float*)d_in[10];
  const float* g1 = (const float*)d_in[11]; const float* be1 = (const float*)d_in[12];
  const float* w2 = (const float*)d_in[13]; const float* b2 = (const float*)d_in[14];
  const float* g2 = (const float*)d_in[15]; const float* be2 = (const float*)d_in[16];
  const float* w3 = (const float*)d_in[17]; const float* b3 = (const float*)d_in[18];
  const float* g3 = (const float*)d_in[19]; const float* be3 = (const float*)d_in[20];
  const float* wo = (const float*)d_in[21]; const float* bo = (const float*)d_in[22];
  float* out = (float*)d_out;

  const int T = T_TOTAL;
  const size_t MB = 1ull << 20;
  char* w8 = (char*)d_ws;
  unsigned short* h0   = (unsigned short*)(w8);              // [T,128] 32MB
  unsigned short* pre  = (unsigned short*)(w8 + 32 * MB);    // [T,512] 128MB
  unsigned short* h1   = (unsigned short*)(w8 + 160 * MB);   // [T,128] 32MB
  unsigned short* xpad = (unsigned short*)(w8 + 192 * MB);   // [T,32]   8MB
  unsigned short* y1   = (unsigned short*)(w8 + 32 * MB);    // reuse pre region
  unsigned short* y2   = (unsigned short*)(w8 + 48 * MB);
  unsigned short* y3   = (unsigned short*)(w8 + 56 * MB);
  float* part1 = (float*)(w8 + 64 * MB);
  float* part2 = (float*)(w8 + 65 * MB);
  float* part3 = (float*)(w8 + 66 * MB);
  float* ac1   = (float*)(w8 + 67 * MB);
  float* ac2   = (float*)(w8 + 67 * MB + 4096);
  float* ac3   = (float*)(w8 + 67 * MB + 8192);

  pad_x<<<T / 256, 256, 0, stream>>>(x, xpad);
  lstm_l0p<<<NBLK, 512, 0, stream>>>(xpad, h0, Whh0, Wih0, bih0, bhh0);
  proj_pre<128><<<(T / 128) * 4, 256, 0, stream>>>(h0, Wih1, bih1, bhh1, pre);
  lstm_seg<<<NBLK, 512, 0, stream>>>(pre, h1, Whh1);

  const int NB = T / 128;
  mlp_mfma<128, 64, false><<<NB, 256, 0, stream>>>(h1, w1, b1, nullptr, y1, part1);
  bn_reduce<<<1, 1024, 0, stream>>>(part1, g1, be1, ac1, NB, 64, 1.f / T);
  mlp_mfma<64, 32, true><<<NB, 256, 0, stream>>>(y1, w2, b2, ac1, y2, part2);
  bn_reduce<<<1, 1024, 0, stream>>>(part2, g2, be2, ac2, NB, 32, 1.f / T);
  mlp_mfma<32, 16, true><<<NB, 256, 0, stream>>>(y2, w3, b3, ac2, y3, part3);
  bn_reduce<<<1, 1024, 0, stream>>>(part3, g3, be3, ac3, NB, 16, 1.f / T);
  final_out<<<T / 256, 256, 0, stream>>>(y3, wo, bo, ac3, out);
}